// Round 18
// baseline (142.413 us; speedup 1.0000x reference)
//
#include <hip/hip_runtime.h>
#include <stdint.h>

typedef unsigned char  u8;
typedef unsigned short u16;
typedef unsigned int u32;

#define NROWS 1024
#define DDIM  1024
#define SLEN  64
#define BATCH 64
#define VOCAB 32000
#define NBN2  125            // 256-wide column blocks
#define PAD_WORD 1

typedef __attribute__((ext_vector_type(4))) float f32x4;
typedef __attribute__((ext_vector_type(2))) float f32x2;
typedef __attribute__((ext_vector_type(2))) long i64x2;

// ---------- fp8 e4m3 converters: HW (gfx940+ cvt_pk) with SW fallback ----------
#if __has_builtin(__builtin_amdgcn_cvt_pk_fp8_f32) && __has_builtin(__builtin_amdgcn_cvt_pk_f32_fp8)
#define HW_FP8 1
__device__ __forceinline__ u32 pk2e4m3(float a, float b) {       // bytes in [15:0]
  return (u32)__builtin_amdgcn_cvt_pk_fp8_f32(a, b, 0, false);
}
__device__ __forceinline__ u32 pk4e4m3(float4 f) {
  int lo = __builtin_amdgcn_cvt_pk_fp8_f32(f.x, f.y, 0, false);
  return (u32)__builtin_amdgcn_cvt_pk_fp8_f32(f.z, f.w, lo, true);
}
template <bool HI>
__device__ __forceinline__ f32x2 up2e4m3(u32 w) {
  return __builtin_amdgcn_cvt_pk_f32_fp8((int)w, HI);   // HI is an ICE here
}
#else
#define HW_FP8 0
__device__ __forceinline__ u32 f2e4m3_sw(float x) {
  union { float f; u32 u; } v; v.f = x;
  const u32 s = (v.u >> 31) << 7;
  const u32 m = v.u & 0x7FFFFFFFu;
  if (m < 0x3C800000u) {
    union { u32 u; float f; } a; a.u = m;
    int q = (int)rintf(a.f * 512.0f);
    return s | (u32)q;
  }
  u32 u2 = m + 0x7FFFFu + ((m >> 20) & 1);
  u32 code = (((u2 >> 23) - 120u) << 3) | ((u2 >> 20) & 7u);
  if (code > 0x7Eu) code = 0x7Eu;
  return s | code;
}
__device__ __forceinline__ u32 pk2e4m3(float a, float b) {
  return f2e4m3_sw(a) | (f2e4m3_sw(b) << 8);
}
__device__ __forceinline__ u32 pk4e4m3(float4 f) {
  return pk2e4m3(f.x, f.y) | (pk2e4m3(f.z, f.w) << 16);
}
__device__ __forceinline__ float e4m3f_sw(u32 b) {
  const u32 e = (b >> 3) & 15u, mm = b & 7u;
  union { u32 u; float f; } c;
  c.u = ((e + 120u) << 23) | (mm << 20);
  float v = e ? c.f : (float)mm * 0.001953125f;
  return (b & 0x80u) ? -v : v;
}
template <bool HI>
__device__ __forceinline__ f32x2 up2e4m3(u32 w) {
  u32 p = HI ? (w >> 16) : w;
  f32x2 r; r.x = e4m3f_sw(p & 255u); r.y = e4m3f_sw((p >> 8) & 255u);
  return r;
}
#endif

// K-interleaved fp8 layout, per 64-k block: 16B unit u holds
// k[8u..8u+8) || k[32+8u..32+8u+8).  (Same permutation for A and B ->
// MFMA dot products pair correctly.)

// -------- kernel 1: fused {p_copy + hidden->fp8} and {W->fp8}, both
//          K-interleaved. convw part: one thread per output 16B unit ->
//          contiguous stores, 2x-touched 64B lines on loads (near-BW). ----
__global__ __launch_bounds__(256) void prep_convw_kernel(
    const float* __restrict__ hidden, const float* __restrict__ w_copy,
    const float* __restrict__ b_copy, u8* __restrict__ hq,
    float* __restrict__ pcopy, const float* __restrict__ W,
    u8* __restrict__ Wq)
{
  const int tid = threadIdx.x;
  if (blockIdx.x < NROWS) {
    // ---- prep: one row per block ----
    const int n = blockIdx.x;
    float4 h = ((const float4*)(hidden + (size_t)n * DDIM))[tid];
    float4 w = ((const float4*)w_copy)[tid];
    const int kb   = tid * 4;
    const int blk  = kb >> 6;
    const int kk   = (kb >> 5) & 1;
    const int u    = (kb >> 3) & 3;
    const int off  = kb & 7;              // 0 or 4
    ((u32*)(hq + (size_t)n * DDIM + blk * 64 + u * 16 + kk * 8 + off))[0] = pk4e4m3(h);
    float d = h.x * w.x + h.y * w.y + h.z * w.z + h.w * w.w;
    #pragma unroll
    for (int m = 1; m < 64; m <<= 1) d += __shfl_xor(d, m);
    __shared__ float ws4[4];
    if ((tid & 63) == 0) ws4[tid >> 6] = d;
    __syncthreads();
    if (tid == 0) {
      float s = ws4[0] + ws4[1] + ws4[2] + ws4[3] + b_copy[0];
      pcopy[n] = 1.0f / (1.0f + __expf(-s));
    }
    return;
  }
  // ---- convw: one thread per 16B output unit ----
  const int i = (blockIdx.x - NROWS) * 256 + tid;   // 0 .. 2,048,000-1
  if (i >= VOCAB * DDIM / 16) return;
  const int blk = i >> 2;
  const int u   = i & 3;
  const float4* src = (const float4*)(W + (size_t)blk * 64 + u * 8);
  float4 a0 = src[0];
  float4 a1 = src[1];
  float4 b0 = src[8];      // +32 floats
  float4 b1 = src[9];
  uint4 o;
  o.x = pk4e4m3(a0); o.y = pk4e4m3(a1);
  o.z = pk4e4m3(b0); o.w = pk4e4m3(b1);
  ((uint4*)Wq)[i] = o;
}

// -------- kernel 2: 256x256 fp8 GEMM (B^T layout), BK=64, 2-barrier
//          interleaved K-loop, SYMMETRIC 2-deep prefetch: both A(t+2) and
//          B(t+2) staged between the barriers; WV(4) keeps 4 loads in
//          flight across the barrier. exp epilogue -> fp8 + row sums. ----
__global__ __launch_bounds__(512, 2) void gemm_exp_kernel(
    const u8* __restrict__ A, const u8* __restrict__ B,
    float* __restrict__ out, u8* __restrict__ eq,
    float* __restrict__ partial, const int use_q)
{
  __shared__ u8 lA[2][16384];     // [dbuf][256 rows x 64 B]
  __shared__ u8 lB[2][16384];
  __shared__ float rowacc[4][256];

  const int tid  = threadIdx.x;
  const int lane = tid & 63;
  const int wid  = tid >> 6;        // 0..7
  const int wm   = wid >> 2;        // 0..1  (M)
  const int wn   = wid & 3;         // 0..3  (N)
  const int al   = lane & 15;
  const int ks   = lane >> 4;       // 0..3

  // bijective XCD-chunked swizzle for 500 blocks (q=62, r=4)
  const int orig = blockIdx.x;
  const int xcd  = orig & 7;
  const int idx  = orig >> 3;
  const int wg   = (xcd < 4 ? xcd * 63 : 252 + (xcd - 4) * 62) + idx;
  const int bm   = wg & 3;          // 4 M-blocks
  const int bn   = wg >> 2;         // 125 N-blocks

  const u8* Abase = A + (size_t)(bm * 256) * DDIM;
  const u8* Bbase = B + (size_t)(bn * 256) * DDIM;

  // staging: 1024 16B-units/tile; thread covers units sA and sA+512
  const int sA = wid * 64 + lane;             // 0..511
  const int rA = sA >> 2;                     // row 0..127 (and +128)
  const int cA = (lane & 3) ^ ((rA >> 1) & 3);  // pre-swizzled source unit

#define GLL(gp, lp) __builtin_amdgcn_global_load_lds( \
    (const __attribute__((address_space(1))) u32*)(gp), \
    (__attribute__((address_space(3))) u32*)(lp), 16, 0, 0)
#define STAGE_T(gbase, lptr, kt) do { \
    GLL((gbase) + (size_t)rA * DDIM + (kt) + cA * 16, (lptr) + sA * 16); \
    GLL((gbase) + (size_t)(rA + 128) * DDIM + (kt) + cA * 16, (lptr) + 8192 + sA * 16); \
  } while (0)

#define WL(n) do { asm volatile("s_waitcnt lgkmcnt(" #n ")" ::: "memory"); \
                   __builtin_amdgcn_sched_barrier(0); } while (0)
#define WV(n) do { asm volatile("s_waitcnt vmcnt(" #n ")" ::: "memory"); \
                   __builtin_amdgcn_sched_barrier(0); } while (0)
#define BAR() do { __builtin_amdgcn_sched_barrier(0); \
                   __builtin_amdgcn_s_barrier(); \
                   __builtin_amdgcn_sched_barrier(0); } while (0)

  // fragment read: one b128 at row r, phys unit ks ^ ((r>>1)&3) -> both kk halves
#define RD_FR(dst, buf, rbase, cnt) do { \
    _Pragma("unroll") \
    for (int i_ = 0; i_ < (cnt); ++i_) { \
      const int r_ = (rbase) + i_ * 16 + al; \
      i64x2 v_ = *(const i64x2*)((buf) + r_ * 64 + (ks ^ ((r_ >> 1) & 3)) * 16); \
      dst[i_][0] = v_.x; dst[i_][1] = v_.y; \
    } } while (0)

#define MM(AF, BF, r0, c0) do { \
    __builtin_amdgcn_s_setprio(1); \
    _Pragma("unroll") \
    for (int mi = 0; mi < 4; ++mi) \
      _Pragma("unroll") \
      for (int ni = 0; ni < 2; ++ni) \
        _Pragma("unroll") \
        for (int kk = 0; kk < 2; ++kk) \
          acc[(r0) + mi][(c0) + ni] = __builtin_amdgcn_mfma_f32_16x16x32_fp8_fp8( \
              AF[mi][kk], BF[ni][kk], acc[(r0) + mi][(c0) + ni], 0, 0, 0); \
    __builtin_amdgcn_s_setprio(0); \
  } while (0)

  u8* lAc = &lA[0][0]; u8* lBc = &lB[0][0];
  u8* lAn = &lA[1][0]; u8* lBn = &lB[1][0];

  f32x4 acc[8][4];
  #pragma unroll
  for (int i = 0; i < 8; ++i)
    #pragma unroll
    for (int j = 0; j < 4; ++j)
      acc[i][j] = (f32x4){0.f, 0.f, 0.f, 0.f};

  long alo[4][2], ahi[4][2], b0f[2][2], b1f[2][2];

  // ---- prologue: tile0 A+B, tile1 A+B ----
  STAGE_T(Abase, lAc, 0);       // vm 2
  STAGE_T(Bbase, lBc, 0);       // vm 4
  STAGE_T(Abase, lAn, 64);      // vm 6
  STAGE_T(Bbase, lBn, 64);      // vm 8
  WV(4);                        // A0,B0 landed; A1,B1 flying
  BAR();
  RD_FR(alo, lAc, wm * 128, 4);
  RD_FR(b0f, lBc, wn * 64, 2);
  RD_FR(b1f, lBc, wn * 64 + 32, 2);     // lgkm 8 outstanding

  for (int t = 0; t < 15; ++t) {
    const int kt2 = (t + 2) * 64;
    // entry: vm = [A(t+1) 2, B(t+1) 2]; lgkm = 8 (alo 4, b0 2, b1 2)
    WL(2);                                  // alo+b0 ready (b1 flying)
    MM(alo, b0f, 0, 0);
    RD_FR(ahi, lAc, wm * 128 + 64, 4);      // lgkm: b1 2 + ahi 4
    WL(4);                                  // b1 ready (ahi flying)
    MM(alo, b1f, 0, 2);
    WL(0);                                  // ahi ready; all cur A+B reads retired
    MM(ahi, b0f, 4, 0);
    BAR();                                  // every wave done reading cur buffers
    if (t < 14) {
      STAGE_T(Abase, lAc, kt2);             // overwrite cur A for t+2
      STAGE_T(Bbase, lBc, kt2);             // overwrite cur B for t+2
    }
    if (t < 14) { WV(4); } else { WV(0); }  // retire A(t+1)+B(t+1); (t+2) flies
    BAR();                                  // next buffers visible to all
    RD_FR(alo, lAn, wm * 128, 4);
    RD_FR(b0f, lBn, wn * 64, 2);
    MM(ahi, b1f, 4, 2);                     // reg-only, overlaps fresh reads
    RD_FR(b1f, lBn, wn * 64 + 32, 2);
    u8* tp = lAc; lAc = lAn; lAn = tp;
    tp = lBc; lBc = lBn; lBn = tp;
  }
  // ---- final tile t=15 (reads already issued at t=14 tail) ----
  WL(2);
  MM(alo, b0f, 0, 0);
  RD_FR(ahi, lAc, wm * 128 + 64, 4);
  WL(4);
  MM(alo, b1f, 0, 2);
  WL(0);
  MM(ahi, b0f, 4, 0);
  MM(ahi, b1f, 4, 2);

#undef GLL
#undef STAGE_T
#undef WL
#undef WV
#undef BAR
#undef RD_FR

  // ---- epilogue: e = exp(logit), write (fp8 via HW cvt_pk, or f32), row-sums ----
  const int g = ks;                 // C/D: row = g*4 + j, col = lane&15
  float rsum[8][4];
  #pragma unroll
  for (int mi = 0; mi < 8; ++mi)
    #pragma unroll
    for (int j = 0; j < 4; ++j) rsum[mi][j] = 0.f;

  const size_t grow0 = (size_t)(bm * 256 + wm * 128);
  const int gcol0 = bn * 256 + wn * 64;
  #pragma unroll
  for (int mi = 0; mi < 8; ++mi) {
    const int rofs = (mi >> 2) * 64 + (mi & 3) * 16 + g * 4;
    #pragma unroll
    for (int j = 0; j < 4; ++j) {
      const size_t row = grow0 + rofs + j;
      float e[4];
      #pragma unroll
      for (int ni = 0; ni < 4; ++ni) {
        const int col = gcol0 + (ni >> 1) * 32 + (ni & 1) * 16 + al;
        float ev = __expf(acc[mi][ni][j]);
        if (col == PAD_WORD) ev = 0.f;
        e[ni] = ev;
        rsum[mi][j] += ev;
      }
      if (use_q) {
        u8* ep = eq + row * VOCAB + gcol0 + al;
        const u32 w01 = pk2e4m3(e[0], e[1]);   // cols +0, +16
        const u32 w23 = pk2e4m3(e[2], e[3]);   // cols +32, +48
        ep[0]  = (u8)(w01 & 255u);
        ep[16] = (u8)((w01 >> 8) & 255u);
        ep[32] = (u8)(w23 & 255u);
        ep[48] = (u8)((w23 >> 8) & 255u);
      } else {
        float* op = out + row * VOCAB + gcol0 + al;
        op[0] = e[0]; op[16] = e[1]; op[32] = e[2]; op[48] = e[3];
      }
    }
  }
  #pragma unroll
  for (int mi = 0; mi < 8; ++mi)
    #pragma unroll
    for (int j = 0; j < 4; ++j) {
      float v = rsum[mi][j];
      v += __shfl_xor(v, 1);
      v += __shfl_xor(v, 2);
      v += __shfl_xor(v, 4);
      v += __shfl_xor(v, 8);
      rsum[mi][j] = v;
    }
  if (al == 0) {
    #pragma unroll
    for (int mi = 0; mi < 8; ++mi)
      #pragma unroll
      for (int j = 0; j < 4; ++j)
        rowacc[wn][wm * 128 + (mi >> 2) * 64 + (mi & 3) * 16 + g * 4 + j] =
            rsum[mi][j];
  }
  __syncthreads();
  if (tid < 256)
    partial[(size_t)bn * NROWS + bm * 256 + tid] =
        rowacc[0][tid] + rowacc[1][tid] + rowacc[2][tid] + rowacc[3][tid];
}

// -------- kernel 3 (fused finish): rowsum + normalize + scatter --------
// Block (n, quarter q) owns cols [q*8000, (q+1)*8000) of row n.
__global__ __launch_bounds__(256) void finish_kernel(
    const u8* __restrict__ eq, const float* __restrict__ partial,
    const float* __restrict__ pcopy, const float* __restrict__ attn,
    const int* __restrict__ src, float* __restrict__ out)
{
  const int bid = blockIdx.x;       // 0..4095
  const int n   = bid >> 2;
  const int q   = bid & 3;
  const int tid = threadIdx.x;

  __shared__ float w4[4];
  __shared__ float sc_sh, of_sh, pc_sh;

  float v = 0.f;
  if (tid < NBN2 * 2) v = partial[(size_t)tid * NROWS + n];   // 250 partials
  #pragma unroll
  for (int m = 1; m < 64; m <<= 1) v += __shfl_xor(v, m);
  if ((tid & 63) == 0) w4[tid >> 6] = v;
  __syncthreads();
  if (tid == 0) {
    const float s = w4[0] + w4[1] + w4[2] + w4[3];
    const float p = pcopy[n];
    sc_sh = (1.0f - p) / s;
    of_sh = (1.0f - p) * 1e-20f;
    pc_sh = p;
  }
  __syncthreads();
  const float sc = sc_sh, of = of_sh;

  const u8* erow = eq + (size_t)n * VOCAB;
  float* orow = out + (size_t)n * VOCAB;
  // quarter = 8000 cols = 500 uint4 units of 16 fp8 each
  for (int u = tid; u < 500; u += 256) {
    const int iu = q * 500 + u;
    uint4 vv = ((const uint4*)erow)[iu];
    const u32 w[4] = {vv.x, vv.y, vv.z, vv.w};
    #pragma unroll
    for (int k = 0; k < 4; ++k) {
      f32x2 lo = up2e4m3<false>(w[k]);
      f32x2 hi = up2e4m3<true>(w[k]);
      float4 o;
      o.x = lo.x * sc + of;
      o.y = lo.y * sc + of;
      o.z = hi.x * sc + of;
      o.w = hi.y * sc + of;
      ((float4*)orow)[iu * 4 + k] = o;
    }
  }
  __syncthreads();      // drains the stores above (barrier waits vmcnt(0))
  if (tid < SLEN) {
    const int b = n & (BATCH - 1);
    const int vtok = src[tid * BATCH + b];
    if (vtok >= q * 8000 && vtok < (q + 1) * 8000) {
      atomicAdd(orow + vtok, pc_sh * attn[(size_t)n * SLEN + tid]);
    }
  }
}

// ---------------- fallback kernels (use_q == 0 path) ----------------
__global__ __launch_bounds__(256) void rowsum_kernel(
    const float* __restrict__ partial, const float* __restrict__ pcopy,
    float* __restrict__ scale, float* __restrict__ ofs)
{
  const int n = blockIdx.x * 256 + threadIdx.x;
  if (n >= NROWS) return;
  float s = 0.f;
  for (int j = 0; j < NBN2; ++j) s += partial[(size_t)j * NROWS + n];
  const float p = pcopy[n];
  scale[n] = (1.0f - p) / s;
  ofs[n]   = (1.0f - p) * 1e-20f;
}

__global__ __launch_bounds__(256) void norm_kernel(
    float* __restrict__ out, const float* __restrict__ scale,
    const float* __restrict__ ofs)
{
  const int total4 = NROWS * VOCAB / 4;
  const int stride = gridDim.x * blockDim.x;
  for (int i = blockIdx.x * 256 + threadIdx.x; i < total4; i += stride) {
    const int n = i / (VOCAB / 4);
    float4* p = (float4*)out + i;
    float4 v = *p;
    const float sc = scale[n], of = ofs[n];
    v.x = v.x * sc + of;
    v.y = v.y * sc + of;
    v.z = v.z * sc + of;
    v.w = v.w * sc + of;
    *p = v;
  }
}

__global__ __launch_bounds__(256) void scatter_kernel(
    float* __restrict__ out, const float* __restrict__ attn,
    const int* __restrict__ src, const float* __restrict__ pcopy)
{
  const int t = blockIdx.x * 256 + threadIdx.x;   // 65536 total
  const int n = t >> 6;
  const int s = t & 63;
  const int b = n & (BATCH - 1);
  const int v = src[s * BATCH + b];
  const float w = pcopy[n] * attn[(size_t)n * SLEN + s];
  atomicAdd(out + (size_t)n * VOCAB + v, w);
}

extern "C" void kernel_launch(void* const* d_in, const int* in_sizes, int n_in,
                              void* d_out, int out_size, void* d_ws, size_t ws_size,
                              hipStream_t stream) {
  const float* hidden = (const float*)d_in[0];
  const float* attn   = (const float*)d_in[1];
  const int*   src    = (const int*)d_in[2];
  const float* W      = (const float*)d_in[3];
  const float* w_copy = (const float*)d_in[4];
  const float* b_copy = (const float*)d_in[5];
  float* out = (float*)d_out;

  char* ws = (char*)d_ws;
  u8*    Wq      = (u8*)ws;                                    // 32,768,000 B
  u8*    hq      = (u8*)(ws + 32768000);                       //  1,048,576 B
  float* pcopy   = (float*)(ws + 33816576);                    //      4,096 B
  float* partial = (float*)(ws + 33820672);                    //  1,024,000 B
  float* scale   = (float*)(ws + 34844672);                    //      4,096 B
  float* ofs     = (float*)(ws + 34848768);                    //      4,096 B
  u8*    eq      = (u8*)(ws + 34852864);                       // 32,768,000 B
  const size_t need_q = 34852864ull + 32768000ull;
  const int use_q = (ws_size >= need_q) ? 1 : 0;

  const int conv_blocks = (VOCAB * DDIM / 16 + 255) / 256;     // 8000
  prep_convw_kernel<<<NROWS + conv_blocks, 256, 0, stream>>>(
      hidden, w_copy, b_copy, hq, pcopy, W, Wq);
  gemm_exp_kernel<<<4 * NBN2, 512, 0, stream>>>(hq, Wq, out, eq, partial, use_q);
  if (use_q) {
    finish_kernel<<<NROWS * 4, 256, 0, stream>>>(eq, partial, pcopy, attn, src, out);
  } else {
    rowsum_kernel<<<(NROWS + 255) / 256, 256, 0, stream>>>(partial, pcopy, scale, ofs);
    norm_kernel<<<2048, 256, 0, stream>>>(out, scale, ofs);
    scatter_kernel<<<NROWS * SLEN / 256, 256, 0, stream>>>(out, attn, src, pcopy);
  }
}

// Round 19
// 139.794 us; speedup vs baseline: 1.0187x; 1.0187x over previous
//
#include <hip/hip_runtime.h>
#include <stdint.h>

typedef unsigned char  u8;
typedef unsigned short u16;
typedef unsigned int u32;

#define NROWS 1024
#define DDIM  1024
#define SLEN  64
#define BATCH 64
#define VOCAB 32000
#define NBN2  125            // 256-wide column blocks
#define PAD_WORD 1

typedef __attribute__((ext_vector_type(4))) float f32x4;
typedef __attribute__((ext_vector_type(2))) float f32x2;
typedef __attribute__((ext_vector_type(2))) long i64x2;

// ---------- fp8 e4m3 converters: HW (gfx940+ cvt_pk) with SW fallback ----------
#if __has_builtin(__builtin_amdgcn_cvt_pk_fp8_f32) && __has_builtin(__builtin_amdgcn_cvt_pk_f32_fp8)
#define HW_FP8 1
__device__ __forceinline__ u32 pk2e4m3(float a, float b) {       // bytes in [15:0]
  return (u32)__builtin_amdgcn_cvt_pk_fp8_f32(a, b, 0, false);
}
__device__ __forceinline__ u32 pk4e4m3(float4 f) {
  int lo = __builtin_amdgcn_cvt_pk_fp8_f32(f.x, f.y, 0, false);
  return (u32)__builtin_amdgcn_cvt_pk_fp8_f32(f.z, f.w, lo, true);
}
template <bool HI>
__device__ __forceinline__ f32x2 up2e4m3(u32 w) {
  return __builtin_amdgcn_cvt_pk_f32_fp8((int)w, HI);   // HI is an ICE here
}
#else
#define HW_FP8 0
__device__ __forceinline__ u32 f2e4m3_sw(float x) {
  union { float f; u32 u; } v; v.f = x;
  const u32 s = (v.u >> 31) << 7;
  const u32 m = v.u & 0x7FFFFFFFu;
  if (m < 0x3C800000u) {
    union { u32 u; float f; } a; a.u = m;
    int q = (int)rintf(a.f * 512.0f);
    return s | (u32)q;
  }
  u32 u2 = m + 0x7FFFFu + ((m >> 20) & 1);
  u32 code = (((u2 >> 23) - 120u) << 3) | ((u2 >> 20) & 7u);
  if (code > 0x7Eu) code = 0x7Eu;
  return s | code;
}
__device__ __forceinline__ u32 pk2e4m3(float a, float b) {
  return f2e4m3_sw(a) | (f2e4m3_sw(b) << 8);
}
__device__ __forceinline__ u32 pk4e4m3(float4 f) {
  return pk2e4m3(f.x, f.y) | (pk2e4m3(f.z, f.w) << 16);
}
__device__ __forceinline__ float e4m3f_sw(u32 b) {
  const u32 e = (b >> 3) & 15u, mm = b & 7u;
  union { u32 u; float f; } c;
  c.u = ((e + 120u) << 23) | (mm << 20);
  float v = e ? c.f : (float)mm * 0.001953125f;
  return (b & 0x80u) ? -v : v;
}
template <bool HI>
__device__ __forceinline__ f32x2 up2e4m3(u32 w) {
  u32 p = HI ? (w >> 16) : w;
  f32x2 r; r.x = e4m3f_sw(p & 255u); r.y = e4m3f_sw((p >> 8) & 255u);
  return r;
}
#endif

// K-interleaved fp8 layout, per 64-k block: 16B unit u holds
// k[8u..8u+8) || k[32+8u..32+8u+8).  (Same permutation for A and B ->
// MFMA dot products pair correctly.)

// -------- kernel 1: fused {p_copy + hidden->fp8} and {W->fp8}, both
//          K-interleaved. convw part: one thread per output 16B unit ->
//          contiguous stores, 2x-touched 64B lines on loads (near-BW). ----
__global__ __launch_bounds__(256) void prep_convw_kernel(
    const float* __restrict__ hidden, const float* __restrict__ w_copy,
    const float* __restrict__ b_copy, u8* __restrict__ hq,
    float* __restrict__ pcopy, const float* __restrict__ W,
    u8* __restrict__ Wq)
{
  const int tid = threadIdx.x;
  if (blockIdx.x < NROWS) {
    // ---- prep: one row per block ----
    const int n = blockIdx.x;
    float4 h = ((const float4*)(hidden + (size_t)n * DDIM))[tid];
    float4 w = ((const float4*)w_copy)[tid];
    const int kb   = tid * 4;
    const int blk  = kb >> 6;
    const int kk   = (kb >> 5) & 1;
    const int u    = (kb >> 3) & 3;
    const int off  = kb & 7;              // 0 or 4
    ((u32*)(hq + (size_t)n * DDIM + blk * 64 + u * 16 + kk * 8 + off))[0] = pk4e4m3(h);
    float d = h.x * w.x + h.y * w.y + h.z * w.z + h.w * w.w;
    #pragma unroll
    for (int m = 1; m < 64; m <<= 1) d += __shfl_xor(d, m);
    __shared__ float ws4[4];
    if ((tid & 63) == 0) ws4[tid >> 6] = d;
    __syncthreads();
    if (tid == 0) {
      float s = ws4[0] + ws4[1] + ws4[2] + ws4[3] + b_copy[0];
      pcopy[n] = 1.0f / (1.0f + __expf(-s));
    }
    return;
  }
  // ---- convw: one thread per 16B output unit ----
  const int i = (blockIdx.x - NROWS) * 256 + tid;   // 0 .. 2,048,000-1
  if (i >= VOCAB * DDIM / 16) return;
  const int blk = i >> 2;
  const int u   = i & 3;
  const float4* src = (const float4*)(W + (size_t)blk * 64 + u * 8);
  float4 a0 = src[0];
  float4 a1 = src[1];
  float4 b0 = src[8];      // +32 floats
  float4 b1 = src[9];
  uint4 o;
  o.x = pk4e4m3(a0); o.y = pk4e4m3(a1);
  o.z = pk4e4m3(b0); o.w = pk4e4m3(b1);
  ((uint4*)Wq)[i] = o;
}

// -------- kernel 2: 256x256 fp8 GEMM (B^T layout), BK=64, 2-barrier
//          interleaved K-loop (r17-proven: B staged early-in-tile 1-deep,
//          A staged between barriers 2-deep). Both operands via
//          global_load_lds into [256 rows][64 B] tiles; K-interleaved units
//          -> frag reads are single ds_read_b128 (conflict-free with
//          X(r)=(r>>1)&3 swizzle on BOTH gload_lds source and ds_read).
//          exp epilogue -> fp8 e4m3 (HW cvt_pk) + per-block row sums. ----
__global__ __launch_bounds__(512, 2) void gemm_exp_kernel(
    const u8* __restrict__ A, const u8* __restrict__ B,
    float* __restrict__ out, u8* __restrict__ eq,
    float* __restrict__ partial, const int use_q)
{
  __shared__ u8 lA[2][16384];     // [dbuf][256 rows x 64 B]
  __shared__ u8 lB[2][16384];
  __shared__ float rowacc[4][256];

  const int tid  = threadIdx.x;
  const int lane = tid & 63;
  const int wid  = tid >> 6;        // 0..7
  const int wm   = wid >> 2;        // 0..1  (M)
  const int wn   = wid & 3;         // 0..3  (N)
  const int al   = lane & 15;
  const int ks   = lane >> 4;       // 0..3

  // bijective XCD-chunked swizzle for 500 blocks (q=62, r=4)
  const int orig = blockIdx.x;
  const int xcd  = orig & 7;
  const int idx  = orig >> 3;
  const int wg   = (xcd < 4 ? xcd * 63 : 252 + (xcd - 4) * 62) + idx;
  const int bm   = wg & 3;          // 4 M-blocks
  const int bn   = wg >> 2;         // 125 N-blocks

  const u8* Abase = A + (size_t)(bm * 256) * DDIM;
  const u8* Bbase = B + (size_t)(bn * 256) * DDIM;

  // staging: 1024 16B-units/tile; thread covers units sA and sA+512
  const int sA = wid * 64 + lane;             // 0..511
  const int rA = sA >> 2;                     // row 0..127 (and +128)
  const int cA = (lane & 3) ^ ((rA >> 1) & 3);  // pre-swizzled source unit

#define GLL(gp, lp) __builtin_amdgcn_global_load_lds( \
    (const __attribute__((address_space(1))) u32*)(gp), \
    (__attribute__((address_space(3))) u32*)(lp), 16, 0, 0)
#define STAGE_T(gbase, lptr, kt) do { \
    GLL((gbase) + (size_t)rA * DDIM + (kt) + cA * 16, (lptr) + sA * 16); \
    GLL((gbase) + (size_t)(rA + 128) * DDIM + (kt) + cA * 16, (lptr) + 8192 + sA * 16); \
  } while (0)

#define WL(n) do { asm volatile("s_waitcnt lgkmcnt(" #n ")" ::: "memory"); \
                   __builtin_amdgcn_sched_barrier(0); } while (0)
#define WV(n) do { asm volatile("s_waitcnt vmcnt(" #n ")" ::: "memory"); \
                   __builtin_amdgcn_sched_barrier(0); } while (0)
#define BAR() do { __builtin_amdgcn_sched_barrier(0); \
                   __builtin_amdgcn_s_barrier(); \
                   __builtin_amdgcn_sched_barrier(0); } while (0)

  // fragment read: one b128 at row r, phys unit ks ^ ((r>>1)&3) -> both kk halves
#define RD_FR(dst, buf, rbase, cnt) do { \
    _Pragma("unroll") \
    for (int i_ = 0; i_ < (cnt); ++i_) { \
      const int r_ = (rbase) + i_ * 16 + al; \
      i64x2 v_ = *(const i64x2*)((buf) + r_ * 64 + (ks ^ ((r_ >> 1) & 3)) * 16); \
      dst[i_][0] = v_.x; dst[i_][1] = v_.y; \
    } } while (0)

#define MM(AF, BF, r0, c0) do { \
    __builtin_amdgcn_s_setprio(1); \
    _Pragma("unroll") \
    for (int mi = 0; mi < 4; ++mi) \
      _Pragma("unroll") \
      for (int ni = 0; ni < 2; ++ni) \
        _Pragma("unroll") \
        for (int kk = 0; kk < 2; ++kk) \
          acc[(r0) + mi][(c0) + ni] = __builtin_amdgcn_mfma_f32_16x16x32_fp8_fp8( \
              AF[mi][kk], BF[ni][kk], acc[(r0) + mi][(c0) + ni], 0, 0, 0); \
    __builtin_amdgcn_s_setprio(0); \
  } while (0)

  u8* lAc = &lA[0][0]; u8* lBc = &lB[0][0];
  u8* lAn = &lA[1][0]; u8* lBn = &lB[1][0];

  f32x4 acc[8][4];
  #pragma unroll
  for (int i = 0; i < 8; ++i)
    #pragma unroll
    for (int j = 0; j < 4; ++j)
      acc[i][j] = (f32x4){0.f, 0.f, 0.f, 0.f};

  long alo[4][2], ahi[4][2], b0f[2][2], b1f[2][2];

  // ---- prologue: tile0 A+B, tile1 A ----
  STAGE_T(Abase, lAc, 0);       // vm 2
  STAGE_T(Bbase, lBc, 0);       // vm 4
  STAGE_T(Abase, lAn, 64);      // vm 6
  WV(2);                        // A0,B0 landed; A1 flying
  BAR();
  RD_FR(alo, lAc, wm * 128, 4);
  RD_FR(b0f, lBc, wn * 64, 2);
  RD_FR(b1f, lBc, wn * 64 + 32, 2);     // lgkm 8 outstanding

  for (int t = 0; t < 15; ++t) {
    const int kt1 = (t + 1) * 64;
    const int kt2 = (t + 2) * 64;
    // entry: vm = [A(t+1) 2]; lgkm = 8 (alo 4, b0 2, b1 2)
    WL(2);                                  // alo+b0 ready (b1 flying)
    MM(alo, b0f, 0, 0);
    STAGE_T(Bbase, lBn, kt1);               // vm: [A(t+1) 2, B(t+1) 2]
    RD_FR(ahi, lAc, wm * 128 + 64, 4);      // lgkm: b1 2 + ahi 4
    WL(4);                                  // b1 ready (ahi flying)
    MM(alo, b1f, 0, 2);
    WL(0);                                  // ahi ready; all cur reads retired
    MM(ahi, b0f, 4, 0);
    BAR();                                  // every wave done reading cur A
    if (t < 14) STAGE_T(Abase, lAc, kt2);   // overwrite cur A for t+2
    if (t < 14) { WV(2); } else { WV(0); }  // A(t+1)+B(t+1) landed
    BAR();                                  // next buffers visible to all
    RD_FR(alo, lAn, wm * 128, 4);
    RD_FR(b0f, lBn, wn * 64, 2);
    MM(ahi, b1f, 4, 2);                     // reg-only, overlaps fresh reads
    RD_FR(b1f, lBn, wn * 64 + 32, 2);
    u8* tp = lAc; lAc = lAn; lAn = tp;
    tp = lBc; lBc = lBn; lBn = tp;
  }
  // ---- final tile t=15 (reads already issued at t=14 tail) ----
  WL(2);
  MM(alo, b0f, 0, 0);
  RD_FR(ahi, lAc, wm * 128 + 64, 4);
  WL(4);
  MM(alo, b1f, 0, 2);
  WL(0);
  MM(ahi, b0f, 4, 0);
  MM(ahi, b1f, 4, 2);

#undef GLL
#undef STAGE_T
#undef WL
#undef WV
#undef BAR
#undef RD_FR

  // ---- epilogue: e = exp(logit), write (fp8 via HW cvt_pk, or f32), row-sums ----
  const int g = ks;                 // C/D: row = g*4 + j, col = lane&15
  float rsum[8][4];
  #pragma unroll
  for (int mi = 0; mi < 8; ++mi)
    #pragma unroll
    for (int j = 0; j < 4; ++j) rsum[mi][j] = 0.f;

  const size_t grow0 = (size_t)(bm * 256 + wm * 128);
  const int gcol0 = bn * 256 + wn * 64;
  #pragma unroll
  for (int mi = 0; mi < 8; ++mi) {
    const int rofs = (mi >> 2) * 64 + (mi & 3) * 16 + g * 4;
    #pragma unroll
    for (int j = 0; j < 4; ++j) {
      const size_t row = grow0 + rofs + j;
      float e[4];
      #pragma unroll
      for (int ni = 0; ni < 4; ++ni) {
        const int col = gcol0 + (ni >> 1) * 32 + (ni & 1) * 16 + al;
        float ev = __expf(acc[mi][ni][j]);
        if (col == PAD_WORD) ev = 0.f;
        e[ni] = ev;
        rsum[mi][j] += ev;
      }
      if (use_q) {
        u8* ep = eq + row * VOCAB + gcol0 + al;
        const u32 w01 = pk2e4m3(e[0], e[1]);   // cols +0, +16
        const u32 w23 = pk2e4m3(e[2], e[3]);   // cols +32, +48
        ep[0]  = (u8)(w01 & 255u);
        ep[16] = (u8)((w01 >> 8) & 255u);
        ep[32] = (u8)(w23 & 255u);
        ep[48] = (u8)((w23 >> 8) & 255u);
      } else {
        float* op = out + row * VOCAB + gcol0 + al;
        op[0] = e[0]; op[16] = e[1]; op[32] = e[2]; op[48] = e[3];
      }
    }
  }
  #pragma unroll
  for (int mi = 0; mi < 8; ++mi)
    #pragma unroll
    for (int j = 0; j < 4; ++j) {
      float v = rsum[mi][j];
      v += __shfl_xor(v, 1);
      v += __shfl_xor(v, 2);
      v += __shfl_xor(v, 4);
      v += __shfl_xor(v, 8);
      rsum[mi][j] = v;
    }
  if (al == 0) {
    #pragma unroll
    for (int mi = 0; mi < 8; ++mi)
      #pragma unroll
      for (int j = 0; j < 4; ++j)
        rowacc[wn][wm * 128 + (mi >> 2) * 64 + (mi & 3) * 16 + g * 4 + j] =
            rsum[mi][j];
  }
  __syncthreads();
  if (tid < 256)
    partial[(size_t)bn * NROWS + bm * 256 + tid] =
        rowacc[0][tid] + rowacc[1][tid] + rowacc[2][tid] + rowacc[3][tid];
}

// -------- kernel 3 (fused finish): rowsum + normalize + scatter --------
// Block (n, quarter q) owns cols [q*8000, (q+1)*8000) of row n.
__global__ __launch_bounds__(256) void finish_kernel(
    const u8* __restrict__ eq, const float* __restrict__ partial,
    const float* __restrict__ pcopy, const float* __restrict__ attn,
    const int* __restrict__ src, float* __restrict__ out)
{
  const int bid = blockIdx.x;       // 0..4095
  const int n   = bid >> 2;
  const int q   = bid & 3;
  const int tid = threadIdx.x;

  __shared__ float w4[4];
  __shared__ float sc_sh, of_sh, pc_sh;

  float v = 0.f;
  if (tid < NBN2 * 2) v = partial[(size_t)tid * NROWS + n];   // 250 partials
  #pragma unroll
  for (int m = 1; m < 64; m <<= 1) v += __shfl_xor(v, m);
  if ((tid & 63) == 0) w4[tid >> 6] = v;
  __syncthreads();
  if (tid == 0) {
    const float s = w4[0] + w4[1] + w4[2] + w4[3];
    const float p = pcopy[n];
    sc_sh = (1.0f - p) / s;
    of_sh = (1.0f - p) * 1e-20f;
    pc_sh = p;
  }
  __syncthreads();
  const float sc = sc_sh, of = of_sh;

  const u8* erow = eq + (size_t)n * VOCAB;
  float* orow = out + (size_t)n * VOCAB;
  // quarter = 8000 cols = 500 uint4 units of 16 fp8 each
  for (int u = tid; u < 500; u += 256) {
    const int iu = q * 500 + u;
    uint4 vv = ((const uint4*)erow)[iu];
    const u32 w[4] = {vv.x, vv.y, vv.z, vv.w};
    #pragma unroll
    for (int k = 0; k < 4; ++k) {
      f32x2 lo = up2e4m3<false>(w[k]);
      f32x2 hi = up2e4m3<true>(w[k]);
      float4 o;
      o.x = lo.x * sc + of;
      o.y = lo.y * sc + of;
      o.z = hi.x * sc + of;
      o.w = hi.y * sc + of;
      ((float4*)orow)[iu * 4 + k] = o;
    }
  }
  __syncthreads();      // drains the stores above (barrier waits vmcnt(0))
  if (tid < SLEN) {
    const int b = n & (BATCH - 1);
    const int vtok = src[tid * BATCH + b];
    if (vtok >= q * 8000 && vtok < (q + 1) * 8000) {
      atomicAdd(orow + vtok, pc_sh * attn[(size_t)n * SLEN + tid]);
    }
  }
}

// ---------------- fallback kernels (use_q == 0 path) ----------------
__global__ __launch_bounds__(256) void rowsum_kernel(
    const float* __restrict__ partial, const float* __restrict__ pcopy,
    float* __restrict__ scale, float* __restrict__ ofs)
{
  const int n = blockIdx.x * 256 + threadIdx.x;
  if (n >= NROWS) return;
  float s = 0.f;
  for (int j = 0; j < NBN2; ++j) s += partial[(size_t)j * NROWS + n];
  const float p = pcopy[n];
  scale[n] = (1.0f - p) / s;
  ofs[n]   = (1.0f - p) * 1e-20f;
}

__global__ __launch_bounds__(256) void norm_kernel(
    float* __restrict__ out, const float* __restrict__ scale,
    const float* __restrict__ ofs)
{
  const int total4 = NROWS * VOCAB / 4;
  const int stride = gridDim.x * blockDim.x;
  for (int i = blockIdx.x * 256 + threadIdx.x; i < total4; i += stride) {
    const int n = i / (VOCAB / 4);
    float4* p = (float4*)out + i;
    float4 v = *p;
    const float sc = scale[n], of = ofs[n];
    v.x = v.x * sc + of;
    v.y = v.y * sc + of;
    v.z = v.z * sc + of;
    v.w = v.w * sc + of;
    *p = v;
  }
}

__global__ __launch_bounds__(256) void scatter_kernel(
    float* __restrict__ out, const float* __restrict__ attn,
    const int* __restrict__ src, const float* __restrict__ pcopy)
{
  const int t = blockIdx.x * 256 + threadIdx.x;   // 65536 total
  const int n = t >> 6;
  const int s = t & 63;
  const int b = n & (BATCH - 1);
  const int v = src[s * BATCH + b];
  const float w = pcopy[n] * attn[(size_t)n * SLEN + s];
  atomicAdd(out + (size_t)n * VOCAB + v, w);
}

extern "C" void kernel_launch(void* const* d_in, const int* in_sizes, int n_in,
                              void* d_out, int out_size, void* d_ws, size_t ws_size,
                              hipStream_t stream) {
  const float* hidden = (const float*)d_in[0];
  const float* attn   = (const float*)d_in[1];
  const int*   src    = (const int*)d_in[2];
  const float* W      = (const float*)d_in[3];
  const float* w_copy = (const float*)d_in[4];
  const float* b_copy = (const float*)d_in[5];
  float* out = (float*)d_out;

  char* ws = (char*)d_ws;
  u8*    Wq      = (u8*)ws;                                    // 32,768,000 B
  u8*    hq      = (u8*)(ws + 32768000);                       //  1,048,576 B
  float* pcopy   = (float*)(ws + 33816576);                    //      4,096 B
  float* partial = (float*)(ws + 33820672);                    //  1,024,000 B
  float* scale   = (float*)(ws + 34844672);                    //      4,096 B
  float* ofs     = (float*)(ws + 34848768);                    //      4,096 B
  u8*    eq      = (u8*)(ws + 34852864);                       // 32,768,000 B
  const size_t need_q = 34852864ull + 32768000ull;
  const int use_q = (ws_size >= need_q) ? 1 : 0;

  const int conv_blocks = (VOCAB * DDIM / 16 + 255) / 256;     // 8000
  prep_convw_kernel<<<NROWS + conv_blocks, 256, 0, stream>>>(
      hidden, w_copy, b_copy, hq, pcopy, W, Wq);
  gemm_exp_kernel<<<4 * NBN2, 512, 0, stream>>>(hq, Wq, out, eq, partial, use_q);
  if (use_q) {
    finish_kernel<<<NROWS * 4, 256, 0, stream>>>(eq, partial, pcopy, attn, src, out);
  } else {
    rowsum_kernel<<<(NROWS + 255) / 256, 256, 0, stream>>>(partial, pcopy, scale, ofs);
    norm_kernel<<<2048, 256, 0, stream>>>(out, scale, ofs);
    scatter_kernel<<<NROWS * SLEN / 256, 256, 0, stream>>>(out, attn, src, pcopy);
  }
}